// Round 1
// baseline (61.490 us; speedup 1.0000x reference)
//
#include <hip/hip_runtime.h>

#define B_ 128
#define E_ 16
#define S_ 32768

constexpr int BLK   = 256;   // threads per block
constexpr int KPT   = 8;     // positions per thread (kernel A)
constexpr int CHUNK = BLK * KPT;        // 2048 positions per block
constexpr int NCHUNK = S_ / CHUNK;      // 16 chunks per batch row

// Order-preserving float <-> uint encoding so atomicMax(uint) == float max.
__device__ __forceinline__ unsigned enc_f(float x) {
    unsigned u = __float_as_uint(x);
    return (u & 0x80000000u) ? ~u : (u | 0x80000000u);
}
__device__ __forceinline__ float dec_f(unsigned e) {
    unsigned u = (e & 0x80000000u) ? (e ^ 0x80000000u) : ~e;
    return __uint_as_float(u);
}

__global__ __launch_bounds__(BLK) void scatter_sum_max(
    const float* __restrict__ events, const int* __restrict__ indices,
    float* __restrict__ out, unsigned* __restrict__ gmax)
{
    const int b  = blockIdx.y;
    const int p0 = blockIdx.x * CHUNK + (int)threadIdx.x;

    float acc[KPT];
#pragma unroll
    for (int k = 0; k < KPT; ++k) acc[k] = 0.0f;

    const float* evb = events + (size_t)b * E_ * S_;

#pragma unroll
    for (int e = 0; e < E_; ++e) {
        const int off = indices[b * E_ + e];          // idx in [0, S)
        const float* ev = evb + (size_t)e * S_ - off; // gather base
#pragma unroll
        for (int k = 0; k < KPT; ++k) {
            const int p = p0 + k * BLK;               // p < S_ always
            if (p >= off) acc[k] += ev[p];            // reads events[b,e,p-off]
        }
    }

    // write raw sums; track thread-local max
    float m = -3.402823466e+38f;
    float* ob = out + (size_t)b * S_;
#pragma unroll
    for (int k = 0; k < KPT; ++k) {
        ob[p0 + k * BLK] = acc[k];
        m = fmaxf(m, acc[k]);
    }

    // wave (64-lane) butterfly reduce
#pragma unroll
    for (int d = 1; d < 64; d <<= 1)
        m = fmaxf(m, __shfl_xor(m, d, 64));

    __shared__ float wmax[BLK / 64];
    if ((threadIdx.x & 63) == 0) wmax[threadIdx.x >> 6] = m;
    __syncthreads();
    if (threadIdx.x == 0) {
        float mm = wmax[0];
#pragma unroll
        for (int w = 1; w < BLK / 64; ++w) mm = fmaxf(mm, wmax[w]);
        atomicMax(gmax + b, enc_f(mm));   // device-scope, cross-XCD safe
    }
}

__global__ __launch_bounds__(256) void normalize_k(
    float* __restrict__ out, const unsigned* __restrict__ gmax)
{
    const int n4 = B_ * S_ / 4;
    float4* o4 = reinterpret_cast<float4*>(out);
    for (int i = blockIdx.x * blockDim.x + threadIdx.x; i < n4;
         i += gridDim.x * blockDim.x) {
        const int b = i / (S_ / 4);
        const float inv = 1.0f / (dec_f(gmax[b]) + 1e-8f);
        float4 v = o4[i];
        v.x *= inv; v.y *= inv; v.z *= inv; v.w *= inv;
        o4[i] = v;
    }
}

extern "C" void kernel_launch(void* const* d_in, const int* in_sizes, int n_in,
                              void* d_out, int out_size, void* d_ws, size_t ws_size,
                              hipStream_t stream) {
    const float* events  = (const float*)d_in[0];
    const int*   indices = (const int*)d_in[1];
    float* out = (float*)d_out;
    unsigned* gmax = (unsigned*)d_ws;

    // ws is poisoned 0xAA once and never re-poisoned: re-init every call.
    // enc==0 decodes below every real float, so 0 is the max-identity.
    hipMemsetAsync(gmax, 0, B_ * sizeof(unsigned), stream);

    dim3 grid(NCHUNK, B_);
    scatter_sum_max<<<grid, BLK, 0, stream>>>(events, indices, out, gmax);

    normalize_k<<<2048, 256, 0, stream>>>(out, gmax);
}

// Round 2
// 39.697 us; speedup vs baseline: 1.5490x; 1.5490x over previous
//
#include <hip/hip_runtime.h>

#define B_ 128
#define E_ 16
#define S_ 32768

constexpr int BLK   = 256;              // threads per block (kernel A)
constexpr int CHUNK = BLK * 8;          // 2048 outputs per block (2 float4/thread)
constexpr int NCH   = S_ / CHUNK;       // 16 chunks per batch row

__global__ __launch_bounds__(BLK) void gather_sum_max(
    const float* __restrict__ events, const int* __restrict__ indices,
    float* __restrict__ out, float* __restrict__ pmax)
{
    const int b  = blockIdx.y;
    const int t  = (int)threadIdx.x;
    const int pA = blockIdx.x * CHUNK + 4 * t;   // first float4 [pA..pA+3]
    const int pB = pA + 4 * BLK;                 // second float4

    float4 accA = {0.f, 0.f, 0.f, 0.f};
    float4 accB = {0.f, 0.f, 0.f, 0.f};

    const float* evb  = events + (size_t)b * (E_ * S_);
    const int*   idxb = indices + b * E_;

#pragma unroll 4
    for (int e = 0; e < E_; ++e) {
        const int off = idxb[e];                  // uniform across block
        const float* row = evb + e * S_ - off;    // row[p] == events[b,e,p-off]

        // ---- vector A ----
        {
            const int s0 = pA - off;
            if (s0 >= 0) {                        // fully valid: one dwordx4
                float4 v = *reinterpret_cast<const float4*>(row + pA);
                accA.x += v.x; accA.y += v.y; accA.z += v.z; accA.w += v.w;
            } else if (s0 > -4) {                 // straddles off: rare scalar path
                if (pA + 1 >= off) accA.y += row[pA + 1];
                if (pA + 2 >= off) accA.z += row[pA + 2];
                if (pA + 3 >= off) accA.w += row[pA + 3];
            }
        }
        // ---- vector B ----
        {
            const int s0 = pB - off;
            if (s0 >= 0) {
                float4 v = *reinterpret_cast<const float4*>(row + pB);
                accB.x += v.x; accB.y += v.y; accB.z += v.z; accB.w += v.w;
            } else if (s0 > -4) {
                if (pB + 1 >= off) accB.y += row[pB + 1];
                if (pB + 2 >= off) accB.z += row[pB + 2];
                if (pB + 3 >= off) accB.w += row[pB + 3];
            }
        }
    }

    // aligned float4 stores of the raw sums
    float* ob = out + (size_t)b * S_;
    *reinterpret_cast<float4*>(ob + pA) = accA;
    *reinterpret_cast<float4*>(ob + pB) = accB;

    // thread-local max of the 8 values
    float m = fmaxf(fmaxf(fmaxf(accA.x, accA.y), fmaxf(accA.z, accA.w)),
                    fmaxf(fmaxf(accB.x, accB.y), fmaxf(accB.z, accB.w)));

    // 64-lane butterfly reduce
#pragma unroll
    for (int d = 1; d < 64; d <<= 1)
        m = fmaxf(m, __shfl_xor(m, d, 64));

    __shared__ float wmax[BLK / 64];
    if ((t & 63) == 0) wmax[t >> 6] = m;
    __syncthreads();
    if (t == 0) {
        float mm = fmaxf(fmaxf(wmax[0], wmax[1]), fmaxf(wmax[2], wmax[3]));
        pmax[b * NCH + blockIdx.x] = mm;   // unique slot: no memset, no atomics
    }
}

__global__ __launch_bounds__(256) void normalize_k(
    float* __restrict__ out, const float* __restrict__ pmax)
{
    const int b = blockIdx.y;
    // redundant per-block reduce of the 16 partial maxes (8 KB total, L2-hot)
    const float* pm = pmax + b * NCH;
    float m = pm[0];
#pragma unroll
    for (int c = 1; c < NCH; ++c) m = fmaxf(m, pm[c]);
    const float inv = 1.0f / (m + 1e-8f);

    const int i = blockIdx.x * blockDim.x + threadIdx.x;   // float4 idx in row
    float4* o4 = reinterpret_cast<float4*>(out + (size_t)b * S_);
    float4 v = o4[i];
    v.x *= inv; v.y *= inv; v.z *= inv; v.w *= inv;
    o4[i] = v;
}

extern "C" void kernel_launch(void* const* d_in, const int* in_sizes, int n_in,
                              void* d_out, int out_size, void* d_ws, size_t ws_size,
                              hipStream_t stream) {
    const float* events  = (const float*)d_in[0];
    const int*   indices = (const int*)d_in[1];
    float* out  = (float*)d_out;
    float* pmax = (float*)d_ws;          // B_*NCH floats = 8 KB

    dim3 gridA(NCH, B_);                 // 16 x 128 = 2048 blocks
    gather_sum_max<<<gridA, BLK, 0, stream>>>(events, indices, out, pmax);

    dim3 gridB(S_ / 4 / 256, B_);        // 32 x 128 = 4096 blocks
    normalize_k<<<gridB, 256, 0, stream>>>(out, pmax);
}